// Round 14
// baseline (326.365 us; speedup 1.0000x reference)
//
#include <hip/hip_runtime.h>
#include <math.h>

namespace {
constexpr int NB = 256;    // batch
constexpr int NR = 1152;   // routes
constexpr int NC = 10;     // output capsules
constexpr int NO = 16;     // output dim
constexpr int NI = 8;      // input dim
constexpr int K1 = NR * NI;   // 9216
constexpr int NN = NC * NO;   // 160
constexpr int KS = 8;         // GEMM1 split-K slices
constexpr int KC = K1 / KS;   // 1152
constexpr int SLICE = NB * NN;   // 40960
constexpr int GRID = 512;        // 2 blocks/CU guaranteed by resources
constexpr int NTILE1 = 16 * NC * KS;   // 1280 GEMM1 tiles
}

using s16x8 = __attribute__((ext_vector_type(8))) short;
using f32x4 = __attribute__((ext_vector_type(4))) float;

__device__ __forceinline__ ushort f2bf(float f) {
    uint u = __float_as_uint(f);
    uint r = (u + 0x7FFFu + ((u >> 16) & 1u)) >> 16;
    return (ushort)r;
}

__device__ __forceinline__ s16x8 pack8(float4 a0, float4 a1) {
    s16x8 r;
    r[0] = (short)f2bf(a0.x); r[1] = (short)f2bf(a0.y);
    r[2] = (short)f2bf(a0.z); r[3] = (short)f2bf(a0.w);
    r[4] = (short)f2bf(a1.x); r[5] = (short)f2bf(a1.y);
    r[6] = (short)f2bf(a1.z); r[7] = (short)f2bf(a1.w);
    return r;
}

__device__ __forceinline__ s16x8 pack8s(float4 a0, float4 a1, float cr) {
    s16x8 r;
    r[0] = (short)f2bf(a0.x * cr); r[1] = (short)f2bf(a0.y * cr);
    r[2] = (short)f2bf(a0.z * cr); r[3] = (short)f2bf(a0.w * cr);
    r[4] = (short)f2bf(a1.x * cr); r[5] = (short)f2bf(a1.y * cr);
    r[6] = (short)f2bf(a1.z * cr); r[7] = (short)f2bf(a1.w * cr);
    return r;
}

// grid barrier: one RELEASE arrive per block, relaxed backoff poll, ACQUIRE exit.
__device__ __forceinline__ void gbar(unsigned* ctr, unsigned target) {
    __syncthreads();
    if (threadIdx.x == 0) {
        __hip_atomic_fetch_add(ctr, 1u, __ATOMIC_RELEASE, __HIP_MEMORY_SCOPE_AGENT);
        while (__hip_atomic_load(ctr, __ATOMIC_RELAXED, __HIP_MEMORY_SCOPE_AGENT) < target)
            __builtin_amdgcn_s_sleep(2);
        (void)__hip_atomic_load(ctr, __ATOMIC_ACQUIRE, __HIP_MEMORY_SCOPE_AGENT);
    }
    __syncthreads();
}

struct Shm {
    ushort T[32][264];        // 16.9 KB (P0 transpose)
    float  red[4][16][16];    // 4 KB (GEMM1 reduce)
    ushort VT[16][264];       // 8.4 KB (GEMM2 B-operand)
    float  smM[NC], smI[NC];  // softmax stats
};

// GEMM1 tile: j -> (mt, c, ks). it==0: B from fp32 W, cr=1/NR.
// it>0: B from Wb bf16, cr=exp(bbuf-m)*inv on the fly.
__device__ __forceinline__ void ka_tile(int j, int it,
                                        const float* __restrict__ x,
                                        const float* __restrict__ W,
                                        const ushort* __restrict__ Wb,
                                        const float* __restrict__ bb,
                                        float* __restrict__ sp,
                                        Shm* sh, int tid, int w, int l) {
    const int mt = j & 15;
    const int rest = j >> 4;
    const int c  = rest % NC;
    const int ks = rest / NC;
    const int m0 = mt * 16;
    const int kb = ks * KC + w * (KC / 4);
    const int lg = l >> 4;
    const float* ap = x + (size_t)(m0 + (l & 15)) * K1 + kb + 8 * lg;

    f32x4 acc = {0.f, 0.f, 0.f, 0.f};
    #pragma unroll
    for (int kk = 0; kk < KC / 4 / 32; ++kk) {   // 9
        const int k = kb + kk * 32 + 8 * lg;
        const int r = k >> 3;
        float4 a0 = *reinterpret_cast<const float4*>(ap + kk * 32);
        float4 a1 = *reinterpret_cast<const float4*>(ap + kk * 32 + 4);
        float cr;
        if (it == 0) cr = 1.0f / NR;
        else         cr = expf(bb[r * NC + c] - sh->smM[c]) * sh->smI[c];
        s16x8 a = pack8s(a0, a1, cr);
        s16x8 b;
        if (it == 0) {
            const float* wp = W + ((size_t)r * NC + c) * 128 + (l & 15) * 8;
            b = pack8(*reinterpret_cast<const float4*>(wp),
                      *reinterpret_cast<const float4*>(wp + 4));
        } else {
            b = *reinterpret_cast<const s16x8*>(
                Wb + ((size_t)r * NC + c) * 128 + (l & 15) * 8);
        }
        acc = __builtin_amdgcn_mfma_f32_16x16x32_bf16(a, b, acc, 0, 0, 0);
    }

    __syncthreads();
    #pragma unroll
    for (int q = 0; q < 4; ++q) sh->red[w][4 * lg + q][l & 15] = acc[q];
    __syncthreads();
    const int row = tid >> 4, col = tid & 15;
    float s2 = sh->red[0][row][col] + sh->red[1][row][col]
             + sh->red[2][row][col] + sh->red[3][row][col];
    sp[(size_t)ks * SLICE + (size_t)(m0 + row) * NN + c * NO + col] = s2;
}

// GEMM2+agree tile: jx in [0,360) -> (36 m-groups, 10 c).
__device__ __forceinline__ void b_tile(int jx,
                                       const ushort* __restrict__ xTbf,
                                       const float* __restrict__ sp,
                                       const float* __restrict__ W,
                                       const float* __restrict__ bbR,
                                       float* __restrict__ bbW,
                                       Shm* sh, int tid, int w, int l) {
    const int c = jx % NC;
    const int jm = jx / NC;   // 0..35

    for (int f = tid; f < NB * NO; f += 256) {
        int b  = f >> 4;
        int oo = f & 15;
        size_t idx = (size_t)b * NN + c * NO + oo;
        float s = 0.0f;
        #pragma unroll
        for (int ks = 0; ks < KS; ++ks) s += sp[(size_t)ks * SLICE + idx];
        float v = s * fabsf(s) / (1.0f + s * s);
        sh->VT[oo][b] = f2bf(v);
    }
    __syncthreads();

    #pragma unroll
    for (int t = 0; t < 4; ++t) {
        const int mt = jm * 16 + w * 4 + t;   // 0..575
        const int m0 = mt * 16;
        const ushort* ap = xTbf + (size_t)(m0 + (l & 15)) * NB + 8 * (l >> 4);
        f32x4 acc = {0.f, 0.f, 0.f, 0.f};
        #pragma unroll
        for (int kk = 0; kk < NB / 32; ++kk) {
            s16x8 a = *reinterpret_cast<const s16x8*>(ap + kk * 32);
            s16x8 b = *reinterpret_cast<const s16x8*>(
                &sh->VT[l & 15][32 * kk + 8 * (l >> 4)]);
            acc = __builtin_amdgcn_mfma_f32_16x16x32_bf16(a, b, acc, 0, 0, 0);
        }
        const int h  = l >> 4, o = l & 15;
        const int r  = (m0 >> 3) + (h >> 1);
        const int i0 = (4 * h) & 7;
        const float4 w4 = *reinterpret_cast<const float4*>(
            W + (((size_t)r * NC + c) * NO + o) * NI + i0);
        float s = acc[0] * w4.x + acc[1] * w4.y + acc[2] * w4.z + acc[3] * w4.w;
        s += __shfl_xor(s, 1);
        s += __shfl_xor(s, 2);
        s += __shfl_xor(s, 4);
        s += __shfl_xor(s, 8);
        s += __shfl_xor(s, 16);
        if (l == 0 || l == 32) {
            int rr = (m0 >> 3) + (l >> 5);
            float val = s * (1.0f / NB);
            bbW[(size_t)rr * NC + c] = (bbR ? bbR[(size_t)rr * NC + c] : 0.0f) + val;
        }
    }
    __syncthreads();
}

// per-block softmax stats for all 10 c's (waves split c's)
__device__ __forceinline__ void smax_stats(const float* __restrict__ bb,
                                           Shm* sh, int w, int l) {
    for (int c = w; c < NC; c += 4) {
        float m = -1e30f;
        for (int r = l; r < NR; r += 64) m = fmaxf(m, bb[r * NC + c]);
        #pragma unroll
        for (int off = 1; off < 64; off <<= 1) m = fmaxf(m, __shfl_xor(m, off));
        float s = 0.0f;
        for (int r = l; r < NR; r += 64) s += expf(bb[r * NC + c] - m);
        #pragma unroll
        for (int off = 1; off < 64; off <<= 1) s += __shfl_xor(s, off);
        if (l == 0) { sh->smM[c] = m; sh->smI[c] = 1.0f / s; }
    }
    __syncthreads();
}

__global__ __launch_bounds__(256, 2) void k_all(const float* __restrict__ x,
                                                const float* __restrict__ W,
                                                float* __restrict__ out,
                                                unsigned* __restrict__ ctr,
                                                float* __restrict__ spart,   // 3 slabs
                                                float* __restrict__ bbuf0,
                                                float* __restrict__ bbuf1,
                                                ushort* __restrict__ xTbf,
                                                ushort* __restrict__ Wb) {
    const int bid = blockIdx.x;
    const int tid = threadIdx.x;
    const int w = tid >> 6, l = tid & 63;
    __shared__ Shm sh;

    float* sp0 = spart;
    float* sp1 = spart + (size_t)KS * SLICE;
    float* sp2 = spart + (size_t)2 * KS * SLICE;

    // ---------- P0: xT transpose + Wb pack + GEMM1(it0) ----------
    for (int j = bid; j < K1 / 32; j += GRID) {
        const int k0 = j * 32;
        #pragma unroll
        for (int jj = 0; jj < 8; ++jj) {
            int f  = jj * 256 + tid;
            int b  = f >> 3;
            int i4 = f & 7;
            float4 v = *reinterpret_cast<const float4*>(
                x + (size_t)b * K1 + k0 + i4 * 4);
            sh.T[i4 * 4 + 0][b] = f2bf(v.x);
            sh.T[i4 * 4 + 1][b] = f2bf(v.y);
            sh.T[i4 * 4 + 2][b] = f2bf(v.z);
            sh.T[i4 * 4 + 3][b] = f2bf(v.w);
        }
        __syncthreads();
        #pragma unroll
        for (int jj = 0; jj < 4; ++jj) {
            int g   = jj * 256 + tid;
            int row = g >> 5;
            int q8  = g & 31;
            *reinterpret_cast<uint4*>(xTbf + (size_t)(k0 + row) * NB + q8 * 8) =
                *reinterpret_cast<const uint4*>(&sh.T[row][q8 * 8]);
        }
        __syncthreads();
    }
    for (size_t e = (size_t)bid * 256 + tid; e < (size_t)NR * NC * NO;
         e += (size_t)GRID * 256) {
        float4 v0 = *reinterpret_cast<const float4*>(W + e * 8);
        float4 v1 = *reinterpret_cast<const float4*>(W + e * 8 + 4);
        s16x8 p = pack8(v0, v1);
        *reinterpret_cast<uint4*>(Wb + e * 8) = *reinterpret_cast<uint4*>(&p);
    }
    for (int j = bid; j < NTILE1; j += GRID)
        ka_tile(j, 0, x, W, Wb, nullptr, sp0, &sh, tid, w, l);
    gbar(ctr, GRID);

    // ---------- P1: GEMM2+agree -> bbuf0 ----------
    if (bid < 360) b_tile(bid, xTbf, sp0, W, nullptr, bbuf0, &sh, tid, w, l);
    gbar(ctr, 2 * GRID);

    // ---------- P2: GEMM1(it1) ----------
    smax_stats(bbuf0, &sh, w, l);
    for (int j = bid; j < NTILE1; j += GRID)
        ka_tile(j, 1, x, W, Wb, bbuf0, sp1, &sh, tid, w, l);
    gbar(ctr, 3 * GRID);

    // ---------- P3: GEMM2+agree -> bbuf1 = bbuf0 + delta ----------
    if (bid < 360) b_tile(bid, xTbf, sp1, W, bbuf0, bbuf1, &sh, tid, w, l);
    gbar(ctr, 4 * GRID);

    // ---------- P4: GEMM1(it2) ----------
    smax_stats(bbuf1, &sh, w, l);
    for (int j = bid; j < NTILE1; j += GRID)
        ka_tile(j, 2, x, W, Wb, bbuf1, sp2, &sh, tid, w, l);
    gbar(ctr, 5 * GRID);

    // ---------- P5: final squash -> out ----------
    if (bid < 160) {
        const int mt = bid & 15;
        const int c  = bid >> 4;
        const int m0 = mt * 16;
        const int row = tid >> 4, col = tid & 15;
        size_t idx = (size_t)(m0 + row) * NN + c * NO + col;
        float s = 0.0f;
        #pragma unroll
        for (int ks = 0; ks < KS; ++ks) s += sp2[(size_t)ks * SLICE + idx];
        out[idx] = s * fabsf(s) / (1.0f + s * s);
    }
}

extern "C" void kernel_launch(void* const* d_in, const int* in_sizes, int n_in,
                              void* d_out, int out_size, void* d_ws, size_t ws_size,
                              hipStream_t stream) {
    const float* x = (const float*)d_in[0];   // [256][9216]
    const float* W = (const float*)d_in[1];   // [1152,10,16,8]
    float* out = (float*)d_out;               // [256][160]

    // ws: ctr(256B) | spart x3 | bbuf0 | bbuf1 | xTbf | Wb  (~11.8 MB)
    unsigned* ctr  = (unsigned*)d_ws;
    float*  spart  = (float*)((char*)d_ws + 256);          // 3*8*40960 f
    float*  bbuf0  = spart + (size_t)3 * KS * SLICE;       // 11520 f
    float*  bbuf1  = bbuf0 + (size_t)NR * NC;              // 11520 f
    ushort* xTbf   = (ushort*)(bbuf1 + (size_t)NR * NC);   // 4.72 MB
    ushort* Wb     = xTbf + (size_t)K1 * NB;               // 2.95 MB

    hipMemsetAsync(ctr, 0, 256, stream);
    k_all<<<GRID, 256, 0, stream>>>(x, W, out, ctr, spart, bbuf0, bbuf1, xTbf, Wb);
}

// Round 15
// 91.725 us; speedup vs baseline: 3.5581x; 3.5581x over previous
//
#include <hip/hip_runtime.h>
#include <math.h>

namespace {
constexpr int NB = 256;    // batch
constexpr int NR = 1152;   // routes
constexpr int NC = 10;     // output capsules
constexpr int NO = 16;     // output dim
constexpr int NI = 8;      // input dim
constexpr int K1 = NR * NI;   // 9216
constexpr int NN = NC * NO;   // 160
constexpr int KW = K1 / 8;    // 1152 per wave (8 waves, full K in block)
}

using s16x8 = __attribute__((ext_vector_type(8))) short;
using f32x4 = __attribute__((ext_vector_type(4))) float;

__device__ __forceinline__ ushort f2bf(float f) {
    uint u = __float_as_uint(f);
    uint r = (u + 0x7FFFu + ((u >> 16) & 1u)) >> 16;
    return (ushort)r;
}

__device__ __forceinline__ s16x8 pack8(float4 a0, float4 a1) {
    s16x8 r;
    r[0] = (short)f2bf(a0.x); r[1] = (short)f2bf(a0.y);
    r[2] = (short)f2bf(a0.z); r[3] = (short)f2bf(a0.w);
    r[4] = (short)f2bf(a1.x); r[5] = (short)f2bf(a1.y);
    r[6] = (short)f2bf(a1.z); r[7] = (short)f2bf(a1.w);
    return r;
}

__device__ __forceinline__ s16x8 pack8s(float4 a0, float4 a1, float cr) {
    s16x8 r;
    r[0] = (short)f2bf(a0.x * cr); r[1] = (short)f2bf(a0.y * cr);
    r[2] = (short)f2bf(a0.z * cr); r[3] = (short)f2bf(a0.w * cr);
    r[4] = (short)f2bf(a1.x * cr); r[5] = (short)f2bf(a1.y * cr);
    r[6] = (short)f2bf(a1.z * cr); r[7] = (short)f2bf(a1.w * cr);
    return r;
}

// 8 packed bf16 (uint4) -> scale by cr -> bf16
__device__ __forceinline__ s16x8 scale8(uint4 u, float cr) {
    s16x8 r;
    r[0] = (short)f2bf(__uint_as_float((u.x & 0xFFFFu) << 16) * cr);
    r[1] = (short)f2bf(__uint_as_float(u.x & 0xFFFF0000u) * cr);
    r[2] = (short)f2bf(__uint_as_float((u.y & 0xFFFFu) << 16) * cr);
    r[3] = (short)f2bf(__uint_as_float(u.y & 0xFFFF0000u) * cr);
    r[4] = (short)f2bf(__uint_as_float((u.z & 0xFFFFu) << 16) * cr);
    r[5] = (short)f2bf(__uint_as_float(u.z & 0xFFFF0000u) * cr);
    r[6] = (short)f2bf(__uint_as_float((u.w & 0xFFFFu) << 16) * cr);
    r[7] = (short)f2bf(__uint_as_float(u.w & 0xFFFF0000u) * cr);
    return r;
}

// GEMM1 full-K per block + in-block squash. Grid (16 mt, 10 c), 512 thr (8 waves,
// wave w takes K-slice w*1152, 36 mfma). IT0 also packs xTbf/Wb/xbf (grid-stride).
// IT0/IT1 write VT[co][b]; IT2 writes out[b][co].
template <int IT>
__global__ __launch_bounds__(512) void k_af(const float* __restrict__ x,
                                            const float* __restrict__ W,
                                            ushort* __restrict__ Wb,
                                            ushort* __restrict__ xbf,
                                            ushort* __restrict__ xTbf,
                                            const float* __restrict__ bb,
                                            ushort* __restrict__ VT,
                                            float* __restrict__ out) {
    const int mt = blockIdx.x;
    const int c  = blockIdx.y;
    const int m0 = mt * 16;
    const int tid = threadIdx.x;
    const int w = tid >> 6, l = tid & 63;

    __shared__ __align__(16) ushort T[32][264];   // IT0 transpose staging
    __shared__ float red[8][16][16];
    __shared__ float crs[NR];
    __shared__ float sred[8], sred2[8];

    if constexpr (IT == 0) {
        const int bid = blockIdx.x + 16 * blockIdx.y;   // 0..159
        // (a) xT transpose: 288 tiles over 160 blocks
        for (int j = bid; j < K1 / 32; j += 160) {
            const int k0 = j * 32;
            #pragma unroll
            for (int jj = 0; jj < 4; ++jj) {
                int f  = jj * 512 + tid;   // [0,2048)
                int b  = f >> 3;
                int i4 = f & 7;
                float4 v = *reinterpret_cast<const float4*>(
                    x + (size_t)b * K1 + k0 + i4 * 4);
                T[i4 * 4 + 0][b] = f2bf(v.x);
                T[i4 * 4 + 1][b] = f2bf(v.y);
                T[i4 * 4 + 2][b] = f2bf(v.z);
                T[i4 * 4 + 3][b] = f2bf(v.w);
            }
            __syncthreads();
            #pragma unroll
            for (int jj = 0; jj < 2; ++jj) {
                int g   = jj * 512 + tid;  // [0,1024)
                int row = g >> 5;
                int q8  = g & 31;
                *reinterpret_cast<uint4*>(xTbf + (size_t)(k0 + row) * NB + q8 * 8) =
                    *reinterpret_cast<const uint4*>(&T[row][q8 * 8]);
            }
            __syncthreads();
        }
        // (b) Wb = bf16(W), grid-stride over 18432 (r,o) rows of 8
        for (int e = bid * 512 + tid; e < NR * NC * NO; e += 160 * 512) {
            const float* wp = W + (size_t)e * 8;
            s16x8 p = pack8(*reinterpret_cast<const float4*>(wp),
                            *reinterpret_cast<const float4*>(wp + 4));
            *reinterpret_cast<uint4*>(Wb + (size_t)e * 8) =
                *reinterpret_cast<uint4*>(&p);
        }
        // (c) xbf = bf16(x), grid-stride over 294912 chunks of 8
        for (int e = bid * 512 + tid; e < NB * (K1 / 8); e += 160 * 512) {
            const float* xp = x + (size_t)e * 8;
            s16x8 p = pack8(*reinterpret_cast<const float4*>(xp),
                            *reinterpret_cast<const float4*>(xp + 4));
            *reinterpret_cast<uint4*>(xbf + (size_t)e * 8) =
                *reinterpret_cast<uint4*>(&p);
        }
    } else {
        // softmax stats for column c + crs (512 threads)
        float m = -1e30f;
        for (int r = tid; r < NR; r += 512) m = fmaxf(m, bb[r * NC + c]);
        #pragma unroll
        for (int off = 1; off < 64; off <<= 1) m = fmaxf(m, __shfl_xor(m, off));
        if (l == 0) sred[w] = m;
        __syncthreads();
        m = sred[0];
        #pragma unroll
        for (int ww = 1; ww < 8; ++ww) m = fmaxf(m, sred[ww]);
        float s = 0.0f;
        for (int r = tid; r < NR; r += 512) s += expf(bb[r * NC + c] - m);
        #pragma unroll
        for (int off = 1; off < 64; off <<= 1) s += __shfl_xor(s, off);
        if (l == 0) sred2[w] = s;
        __syncthreads();
        s = 0.0f;
        #pragma unroll
        for (int ww = 0; ww < 8; ++ww) s += sred2[ww];
        const float inv = 1.0f / s;
        for (int r = tid; r < NR; r += 512)
            crs[r] = expf(bb[r * NC + c] - m) * inv;
        __syncthreads();
    }

    // main GEMM: wave w covers K [w*1152, (w+1)*1152), 36 mfma steps
    const int kb = w * KW;
    const int lg = l >> 4;
    f32x4 acc = {0.f, 0.f, 0.f, 0.f};

    if constexpr (IT == 0) {
        const float* ap = x + (size_t)(m0 + (l & 15)) * K1 + kb + 8 * lg;
        #pragma unroll 4
        for (int kk = 0; kk < KW / 32; ++kk) {
            float4 a0 = *reinterpret_cast<const float4*>(ap + kk * 32);
            float4 a1 = *reinterpret_cast<const float4*>(ap + kk * 32 + 4);
            s16x8 a = pack8s(a0, a1, 1.0f / NR);
            const int r = w * 144 + kk * 4 + lg;
            const float* wp = W + ((size_t)r * NC + c) * 128 + (l & 15) * 8;
            s16x8 b = pack8(*reinterpret_cast<const float4*>(wp),
                            *reinterpret_cast<const float4*>(wp + 4));
            acc = __builtin_amdgcn_mfma_f32_16x16x32_bf16(a, b, acc, 0, 0, 0);
        }
    } else {
        const ushort* ap = xbf + (size_t)(m0 + (l & 15)) * K1 + kb + 8 * lg;
        #pragma unroll 4
        for (int kk = 0; kk < KW / 32; ++kk) {
            uint4 ar = *reinterpret_cast<const uint4*>(ap + kk * 32);
            const int r = w * 144 + kk * 4 + lg;
            s16x8 a = scale8(ar, crs[r]);
            s16x8 b = *reinterpret_cast<const s16x8*>(
                Wb + ((size_t)r * NC + c) * 128 + (l & 15) * 8);
            acc = __builtin_amdgcn_mfma_f32_16x16x32_bf16(a, b, acc, 0, 0, 0);
        }
    }

    __syncthreads();
    #pragma unroll
    for (int q = 0; q < 4; ++q) red[w][4 * lg + q][l & 15] = acc[q];
    __syncthreads();
    if (tid < 256) {
        const int row = tid >> 4, col = tid & 15;
        float s = 0.0f;
        #pragma unroll
        for (int ww = 0; ww < 8; ++ww) s += red[ww][row][col];
        float v = s * fabsf(s) / (1.0f + s * s);
        if constexpr (IT == 2)
            out[(size_t)(m0 + row) * NN + c * NO + col] = v;
        else
            VT[(size_t)(c * NO + col) * NB + m0 + row] = f2bf(v);
    }
}

// GEMM2 + W-contraction -> exclusive bbuf write. Grid (36,10), 256 thr.
// bbW[r,c] = (bbR ? bbR[r,c] : 0) + mean_b(...)
__global__ __launch_bounds__(256) void k_b(const ushort* __restrict__ xTbf,
                                           const ushort* __restrict__ VT,
                                           const float* __restrict__ W,
                                           const float* __restrict__ bbR,
                                           float* __restrict__ bbW) {
    const int c = blockIdx.y;
    const int tid = threadIdx.x;
    const int w = tid >> 6, l = tid & 63;

    __shared__ __align__(16) ushort VTs[16][264];

    for (int e = tid; e < 16 * 32; e += 256) {
        int row = e >> 5, q8 = e & 31;
        *reinterpret_cast<uint4*>(&VTs[row][q8 * 8]) =
            *reinterpret_cast<const uint4*>(VT + (size_t)(c * NO + row) * NB + q8 * 8);
    }
    __syncthreads();

    #pragma unroll
    for (int t = 0; t < 4; ++t) {
        const int mt = blockIdx.x * 16 + w * 4 + t;   // 0..575
        const int m0 = mt * 16;
        const ushort* ap = xTbf + (size_t)(m0 + (l & 15)) * NB + 8 * (l >> 4);
        f32x4 acc = {0.f, 0.f, 0.f, 0.f};
        #pragma unroll
        for (int kk = 0; kk < NB / 32; ++kk) {
            s16x8 a = *reinterpret_cast<const s16x8*>(ap + kk * 32);
            s16x8 b = *reinterpret_cast<const s16x8*>(
                &VTs[l & 15][32 * kk + 8 * (l >> 4)]);
            acc = __builtin_amdgcn_mfma_f32_16x16x32_bf16(a, b, acc, 0, 0, 0);
        }
        const int h  = l >> 4, o = l & 15;
        const int r  = (m0 >> 3) + (h >> 1);
        const int i0 = (4 * h) & 7;
        const float4 w4 = *reinterpret_cast<const float4*>(
            W + (((size_t)r * NC + c) * NO + o) * NI + i0);
        float s = acc[0] * w4.x + acc[1] * w4.y + acc[2] * w4.z + acc[3] * w4.w;
        s += __shfl_xor(s, 1);
        s += __shfl_xor(s, 2);
        s += __shfl_xor(s, 4);
        s += __shfl_xor(s, 8);
        s += __shfl_xor(s, 16);
        if (l == 0 || l == 32) {
            int rr = (m0 >> 3) + (l >> 5);
            float val = s * (1.0f / NB);
            bbW[(size_t)rr * NC + c] =
                (bbR ? bbR[(size_t)rr * NC + c] : 0.0f) + val;
        }
    }
}

extern "C" void kernel_launch(void* const* d_in, const int* in_sizes, int n_in,
                              void* d_out, int out_size, void* d_ws, size_t ws_size,
                              hipStream_t stream) {
    const float* x = (const float*)d_in[0];   // [256][9216]
    const float* W = (const float*)d_in[1];   // [1152,10,16,8]
    float* out = (float*)d_out;               // [256][160]

    // ws: xTbf | Wb | xbf | VT | bbuf0 | bbuf1  (~12.6 MB)
    ushort* xTbf = (ushort*)d_ws;                        // 9216*256 = 4.72 MB
    ushort* Wb   = xTbf + (size_t)K1 * NB;               // 2.95 MB
    ushort* xbf  = Wb + (size_t)NR * NC * NO * NI;       // 4.72 MB
    ushort* VT   = xbf + (size_t)NB * K1;                // 160*256 = 80 KB
    float*  bbuf0 = (float*)(VT + (size_t)NN * NB);      // 11520 f
    float*  bbuf1 = bbuf0 + (size_t)NR * NC;             // 11520 f

    dim3 ga(NB / 16, NC);   // (16,10) = 160 blocks, 512 thr
    dim3 gb(36, NC);        // 360 blocks

    k_af<0><<<ga, 512, 0, stream>>>(x, W, Wb, xbf, xTbf, nullptr, VT, nullptr);
    k_b<<<gb, 256, 0, stream>>>(xTbf, VT, W, nullptr, bbuf0);
    k_af<1><<<ga, 512, 0, stream>>>(x, W, Wb, xbf, xTbf, bbuf0, VT, nullptr);
    k_b<<<gb, 256, 0, stream>>>(xTbf, VT, W, bbuf0, bbuf1);
    k_af<2><<<ga, 512, 0, stream>>>(x, W, Wb, xbf, xTbf, bbuf1, nullptr, out);
}

// Round 16
// 80.600 us; speedup vs baseline: 4.0492x; 1.1380x over previous
//
#include <hip/hip_runtime.h>
#include <math.h>

namespace {
constexpr int NB = 256;    // batch
constexpr int NR = 1152;   // routes
constexpr int NC = 10;     // output capsules
constexpr int NO = 16;     // output dim
constexpr int NI = 8;      // input dim
constexpr int K1 = NR * NI;   // 9216
constexpr int NN = NC * NO;   // 160
constexpr int KS = 8;         // GEMM1 split-K slices (across blocks)
constexpr int KC = K1 / KS;   // 1152 per block
constexpr int RPB = NR / KS;  // 144 r per block
}

using s16x8 = __attribute__((ext_vector_type(8))) short;
using f32x4 = __attribute__((ext_vector_type(4))) float;

__device__ __forceinline__ ushort f2bf(float f) {
    uint u = __float_as_uint(f);
    uint r = (u + 0x7FFFu + ((u >> 16) & 1u)) >> 16;
    return (ushort)r;
}

__device__ __forceinline__ s16x8 pack8(float4 a0, float4 a1) {
    s16x8 r;
    r[0] = (short)f2bf(a0.x); r[1] = (short)f2bf(a0.y);
    r[2] = (short)f2bf(a0.z); r[3] = (short)f2bf(a0.w);
    r[4] = (short)f2bf(a1.x); r[5] = (short)f2bf(a1.y);
    r[6] = (short)f2bf(a1.z); r[7] = (short)f2bf(a1.w);
    return r;
}

__device__ __forceinline__ s16x8 pack8s(float4 a0, float4 a1, float cr) {
    s16x8 r;
    r[0] = (short)f2bf(a0.x * cr); r[1] = (short)f2bf(a0.y * cr);
    r[2] = (short)f2bf(a0.z * cr); r[3] = (short)f2bf(a0.w * cr);
    r[4] = (short)f2bf(a1.x * cr); r[5] = (short)f2bf(a1.y * cr);
    r[6] = (short)f2bf(a1.z * cr); r[7] = (short)f2bf(a1.w * cr);
    return r;
}

// 8 packed bf16 (uint4) -> scale by cr -> bf16  (validated round 15)
__device__ __forceinline__ s16x8 scale8(uint4 u, float cr) {
    s16x8 r;
    r[0] = (short)f2bf(__uint_as_float((u.x & 0xFFFFu) << 16) * cr);
    r[1] = (short)f2bf(__uint_as_float(u.x & 0xFFFF0000u) * cr);
    r[2] = (short)f2bf(__uint_as_float((u.y & 0xFFFFu) << 16) * cr);
    r[3] = (short)f2bf(__uint_as_float(u.y & 0xFFFF0000u) * cr);
    r[4] = (short)f2bf(__uint_as_float((u.z & 0xFFFFu) << 16) * cr);
    r[5] = (short)f2bf(__uint_as_float(u.z & 0xFFFF0000u) * cr);
    r[6] = (short)f2bf(__uint_as_float((u.w & 0xFFFFu) << 16) * cr);
    r[7] = (short)f2bf(__uint_as_float(u.w & 0xFFFF0000u) * cr);
    return r;
}

// GEMM1 K-slice. Grid (16 mt, 10 c, 8 ks); 4 waves sub-split K (288 each, 9 mfma).
// FIRST: A = bf16(x/NR) from fp32, B = bf16(W fp32) on the fly; also packs
//        Wb (bf16 W), xbf (bf16 x) grid-stride, and 288 xT tiles.
// else:  A = scale8(xbf, crs[r]) (bf16 in, one mul, one round); B = Wb direct.
template <bool FIRST>
__global__ __launch_bounds__(256) void k_a(const float* __restrict__ x,
                                           const float* __restrict__ W,
                                           ushort* __restrict__ Wb,
                                           ushort* __restrict__ xbf,
                                           const float* __restrict__ bbuf,
                                           float* __restrict__ spart,
                                           ushort* __restrict__ xTbf) {
    const int m0 = blockIdx.x * 16;
    const int c  = blockIdx.y;
    const int ks = blockIdx.z;
    const int tid = threadIdx.x;
    const int w = tid >> 6, l = tid & 63;

    __shared__ float red[4][16][16];
    __shared__ float crs[RPB];
    __shared__ float sred[4], sred2[4];

    if constexpr (FIRST) {
        // xT prep (first 288 flat blocks)
        __shared__ __align__(16) ushort T[32][264];
        const int bid = blockIdx.x + 16 * blockIdx.y + 160 * blockIdx.z;
        if (bid < K1 / 32) {
            const int k0 = bid * 32;
            #pragma unroll
            for (int j = 0; j < 8; ++j) {
                int f  = j * 256 + tid;
                int b  = f >> 3;
                int i4 = f & 7;
                float4 v = *reinterpret_cast<const float4*>(
                    x + (size_t)b * K1 + k0 + i4 * 4);
                T[i4 * 4 + 0][b] = f2bf(v.x);
                T[i4 * 4 + 1][b] = f2bf(v.y);
                T[i4 * 4 + 2][b] = f2bf(v.z);
                T[i4 * 4 + 3][b] = f2bf(v.w);
            }
            __syncthreads();
            #pragma unroll
            for (int j = 0; j < 4; ++j) {
                int g   = j * 256 + tid;
                int row = g >> 5;
                int q8  = g & 31;
                *reinterpret_cast<uint4*>(xTbf + (size_t)(k0 + row) * NB + q8 * 8) =
                    *reinterpret_cast<const uint4*>(&T[row][q8 * 8]);
            }
        }
        const int nblk = 16 * NC * KS;
        const size_t gs = (size_t)(blockIdx.x + 16 * blockIdx.y + 160 * blockIdx.z) * 256 + tid;
        // Wb = bf16(W), natural layout, coalesced
        for (size_t e = gs; e < (size_t)NR * NC * NO; e += (size_t)nblk * 256) {
            float4 v0 = *reinterpret_cast<const float4*>(W + e * 8);
            float4 v1 = *reinterpret_cast<const float4*>(W + e * 8 + 4);
            s16x8 p = pack8(v0, v1);
            *reinterpret_cast<uint4*>(Wb + e * 8) = *reinterpret_cast<uint4*>(&p);
        }
        // xbf = bf16(x), coalesced
        for (size_t e = gs; e < (size_t)NB * (K1 / 8); e += (size_t)nblk * 256) {
            float4 v0 = *reinterpret_cast<const float4*>(x + e * 8);
            float4 v1 = *reinterpret_cast<const float4*>(x + e * 8 + 4);
            s16x8 p = pack8(v0, v1);
            *reinterpret_cast<uint4*>(xbf + e * 8) = *reinterpret_cast<uint4*>(&p);
        }
    } else {
        // softmax stats over full column c (identical in all blocks) -> crs
        float m = -1e30f;
        for (int r = tid; r < NR; r += 256) m = fmaxf(m, bbuf[r * NC + c]);
        #pragma unroll
        for (int off = 1; off < 64; off <<= 1) m = fmaxf(m, __shfl_xor(m, off));
        if (l == 0) sred[w] = m;
        __syncthreads();
        m = fmaxf(fmaxf(sred[0], sred[1]), fmaxf(sred[2], sred[3]));
        float s = 0.0f;
        for (int r = tid; r < NR; r += 256) s += expf(bbuf[r * NC + c] - m);
        #pragma unroll
        for (int off = 1; off < 64; off <<= 1) s += __shfl_xor(s, off);
        if (l == 0) sred2[w] = s;
        __syncthreads();
        s = sred2[0] + sred2[1] + sred2[2] + sred2[3];
        const float inv = 1.0f / s;
        for (int i = tid; i < RPB; i += 256)
            crs[i] = expf(bbuf[(ks * RPB + i) * NC + c] - m) * inv;
        __syncthreads();
    }

    const int kb = ks * KC + w * (KC / 4);   // wave K base (288)
    const int lg = l >> 4;

    f32x4 acc = {0.f, 0.f, 0.f, 0.f};
    if constexpr (FIRST) {
        const float* ap = x + (size_t)(m0 + (l & 15)) * K1 + kb + 8 * lg;
        #pragma unroll
        for (int kk = 0; kk < KC / 4 / 32; ++kk) {   // 9
            const int k = kb + kk * 32 + 8 * lg;
            const int r = k >> 3;
            float4 a0 = *reinterpret_cast<const float4*>(ap + kk * 32);
            float4 a1 = *reinterpret_cast<const float4*>(ap + kk * 32 + 4);
            s16x8 a = pack8s(a0, a1, 1.0f / NR);
            const float* wp = W + ((size_t)r * NC + c) * 128 + (l & 15) * 8;
            s16x8 b = pack8(*reinterpret_cast<const float4*>(wp),
                            *reinterpret_cast<const float4*>(wp + 4));
            acc = __builtin_amdgcn_mfma_f32_16x16x32_bf16(a, b, acc, 0, 0, 0);
        }
    } else {
        const ushort* ap = xbf + (size_t)(m0 + (l & 15)) * K1 + kb + 8 * lg;
        #pragma unroll
        for (int kk = 0; kk < KC / 4 / 32; ++kk) {   // 9
            const int k = kb + kk * 32 + 8 * lg;
            const int r = k >> 3;
            uint4 ar = *reinterpret_cast<const uint4*>(ap + kk * 32);
            s16x8 a = scale8(ar, crs[r - ks * RPB]);
            s16x8 b = *reinterpret_cast<const s16x8*>(
                Wb + ((size_t)r * NC + c) * 128 + (l & 15) * 8);
            acc = __builtin_amdgcn_mfma_f32_16x16x32_bf16(a, b, acc, 0, 0, 0);
        }
    }

    #pragma unroll
    for (int q = 0; q < 4; ++q) red[w][4 * lg + q][l & 15] = acc[q];
    __syncthreads();
    const int row = tid >> 4, col = tid & 15;
    float s2 = red[0][row][col] + red[1][row][col]
             + red[2][row][col] + red[3][row][col];
    spart[(size_t)ks * (NB * NN) + (size_t)(m0 + row) * NN + c * NO + col] = s2;
}

// K_b: [sum spart -> squash -> VT in LDS] + GEMM2-from-LDS + W-contract ->
// exclusive bbuf update. Grid (36,10).
__global__ __launch_bounds__(256) void k_b(const ushort* __restrict__ xTbf,
                                           const float* __restrict__ spart,
                                           const float* __restrict__ W,
                                           float* __restrict__ bbuf,
                                           int it) {
    const int c = blockIdx.y;
    const int tid = threadIdx.x;
    const int w = tid >> 6, l = tid & 63;

    __shared__ __align__(16) ushort VT[16][264];

    for (int f = tid; f < NB * NO; f += 256) {   // 4096 (b,oo)
        int b  = f >> 4;
        int oo = f & 15;
        size_t idx = (size_t)b * NN + c * NO + oo;
        float s = 0.0f;
        #pragma unroll
        for (int ks = 0; ks < KS; ++ks) s += spart[(size_t)ks * NB * NN + idx];
        float v = s * fabsf(s) / (1.0f + s * s);
        VT[oo][b] = f2bf(v);
    }
    __syncthreads();

    #pragma unroll
    for (int t = 0; t < 4; ++t) {
        const int mt = blockIdx.x * 16 + w * 4 + t;   // 0..575
        const int m0 = mt * 16;
        const ushort* ap = xTbf + (size_t)(m0 + (l & 15)) * NB + 8 * (l >> 4);
        f32x4 acc = {0.f, 0.f, 0.f, 0.f};
        #pragma unroll
        for (int kk = 0; kk < NB / 32; ++kk) {
            s16x8 a = *reinterpret_cast<const s16x8*>(ap + kk * 32);
            s16x8 b = *reinterpret_cast<const s16x8*>(&VT[l & 15][32 * kk + 8 * (l >> 4)]);
            acc = __builtin_amdgcn_mfma_f32_16x16x32_bf16(a, b, acc, 0, 0, 0);
        }
        const int h  = l >> 4, o = l & 15;
        const int r  = (m0 >> 3) + (h >> 1);
        const int i0 = (4 * h) & 7;
        const float4 w4 = *reinterpret_cast<const float4*>(
            W + (((size_t)r * NC + c) * NO + o) * NI + i0);
        float s = acc[0] * w4.x + acc[1] * w4.y + acc[2] * w4.z + acc[3] * w4.w;
        s += __shfl_xor(s, 1);
        s += __shfl_xor(s, 2);
        s += __shfl_xor(s, 4);
        s += __shfl_xor(s, 8);
        s += __shfl_xor(s, 16);
        if (l == 0 || l == 32) {
            int rr = (m0 >> 3) + (l >> 5);
            float val = s * (1.0f / NB);
            if (it > 0) bbuf[(size_t)rr * NC + c] += val;
            else        bbuf[(size_t)rr * NC + c] = val;
        }
    }
}

// final: sum spart slices + squash -> out[b][c][o]. Grid (16,10).
__global__ __launch_bounds__(256) void k_bf(const float* __restrict__ spart,
                                            float* __restrict__ out) {
    const int m0 = blockIdx.x * 16;
    const int c  = blockIdx.y;
    const int row = threadIdx.x >> 4, col = threadIdx.x & 15;
    size_t idx = (size_t)(m0 + row) * NN + c * NO + col;
    float s = 0.0f;
    #pragma unroll
    for (int ks = 0; ks < KS; ++ks) s += spart[(size_t)ks * NB * NN + idx];
    out[idx] = s * fabsf(s) / (1.0f + s * s);
}

extern "C" void kernel_launch(void* const* d_in, const int* in_sizes, int n_in,
                              void* d_out, int out_size, void* d_ws, size_t ws_size,
                              hipStream_t stream) {
    const float* x = (const float*)d_in[0];   // [256][9216]
    const float* W = (const float*)d_in[1];   // [1152,10,16,8]
    float* out = (float*)d_out;               // [256][160]

    // ws: spart | bbuf | xTbf | Wb | xbf  (~13.8 MB)
    float*  spart = (float*)d_ws;                          // 8*40960 f = 1.31 MB
    float*  bbuf  = spart + (size_t)KS * NB * NN;          // 11520 f
    ushort* xTbf  = (ushort*)(bbuf + (size_t)NR * NC);     // 4.72 MB
    ushort* Wb    = xTbf + (size_t)K1 * NB;                // 2.95 MB
    ushort* xbf   = Wb + (size_t)NR * NC * NO * NI;        // 4.72 MB

    dim3 ga(NB / 16, NC, KS);   // (16,10,8) = 1280 blocks
    dim3 gb(36, NC);            // 360 blocks
    dim3 gf(NB / 16, NC);       // 160 blocks

    k_a<true><<<ga, 256, 0, stream>>>(x, W, Wb, xbf, nullptr, spart, xTbf);
    k_b<<<gb, 256, 0, stream>>>(xTbf, spart, W, bbuf, 0);
    k_a<false><<<ga, 256, 0, stream>>>(x, W, Wb, xbf, bbuf, spart, nullptr);
    k_b<<<gb, 256, 0, stream>>>(xTbf, spart, W, bbuf, 1);
    k_a<false><<<ga, 256, 0, stream>>>(x, W, Wb, xbf, bbuf, spart, nullptr);
    k_bf<<<gf, 256, 0, stream>>>(spart, out);
}

// Round 17
// 78.710 us; speedup vs baseline: 4.1464x; 1.0240x over previous
//
#include <hip/hip_runtime.h>
#include <math.h>

namespace {
constexpr int NB = 256;    // batch
constexpr int NR = 1152;   // routes
constexpr int NC = 10;     // output capsules
constexpr int NO = 16;     // output dim
constexpr int NI = 8;      // input dim
constexpr int K1 = NR * NI;   // 9216
constexpr int NN = NC * NO;   // 160
constexpr int KS = 8;         // GEMM1 split-K slices (across blocks)
constexpr int KC = K1 / KS;   // 1152 per block
constexpr int RPB = NR / KS;  // 144 r per block
}

using s16x8 = __attribute__((ext_vector_type(8))) short;
using f32x4 = __attribute__((ext_vector_type(4))) float;

__device__ __forceinline__ ushort f2bf(float f) {
    uint u = __float_as_uint(f);
    uint r = (u + 0x7FFFu + ((u >> 16) & 1u)) >> 16;
    return (ushort)r;
}

__device__ __forceinline__ s16x8 pack8(float4 a0, float4 a1) {
    s16x8 r;
    r[0] = (short)f2bf(a0.x); r[1] = (short)f2bf(a0.y);
    r[2] = (short)f2bf(a0.z); r[3] = (short)f2bf(a0.w);
    r[4] = (short)f2bf(a1.x); r[5] = (short)f2bf(a1.y);
    r[6] = (short)f2bf(a1.z); r[7] = (short)f2bf(a1.w);
    return r;
}

__device__ __forceinline__ s16x8 pack8s(float4 a0, float4 a1, float cr) {
    s16x8 r;
    r[0] = (short)f2bf(a0.x * cr); r[1] = (short)f2bf(a0.y * cr);
    r[2] = (short)f2bf(a0.z * cr); r[3] = (short)f2bf(a0.w * cr);
    r[4] = (short)f2bf(a1.x * cr); r[5] = (short)f2bf(a1.y * cr);
    r[6] = (short)f2bf(a1.z * cr); r[7] = (short)f2bf(a1.w * cr);
    return r;
}

// 8 packed bf16 (uint4) -> scale by cr -> bf16  (validated rounds 15/16)
__device__ __forceinline__ s16x8 scale8(uint4 u, float cr) {
    s16x8 r;
    r[0] = (short)f2bf(__uint_as_float((u.x & 0xFFFFu) << 16) * cr);
    r[1] = (short)f2bf(__uint_as_float(u.x & 0xFFFF0000u) * cr);
    r[2] = (short)f2bf(__uint_as_float((u.y & 0xFFFFu) << 16) * cr);
    r[3] = (short)f2bf(__uint_as_float(u.y & 0xFFFF0000u) * cr);
    r[4] = (short)f2bf(__uint_as_float((u.z & 0xFFFFu) << 16) * cr);
    r[5] = (short)f2bf(__uint_as_float(u.z & 0xFFFF0000u) * cr);
    r[6] = (short)f2bf(__uint_as_float((u.w & 0xFFFFu) << 16) * cr);
    r[7] = (short)f2bf(__uint_as_float(u.w & 0xFFFF0000u) * cr);
    return r;
}

// GEMM1 K-slice, c-PAIRED (N=32): grid (16 mt, 5 cp, 8 ks) = 640 blocks.
// 4 waves sub-split K (288 each, 9 steps x 2 mfma). A-fragment loaded ONCE,
// used for both c's. FIRST also packs Wb/xbf and 288 xT tiles.
template <bool FIRST>
__global__ __launch_bounds__(256) void k_a(const float* __restrict__ x,
                                           const float* __restrict__ W,
                                           ushort* __restrict__ Wb,
                                           ushort* __restrict__ xbf,
                                           const float* __restrict__ bbufT,
                                           float* __restrict__ spart,
                                           ushort* __restrict__ xTbf) {
    const int m0 = blockIdx.x * 16;
    const int c0 = blockIdx.y * 2;
    const int ks = blockIdx.z;
    const int tid = threadIdx.x;
    const int w = tid >> 6, l = tid & 63;

    __shared__ float red[2][4][16][16];
    __shared__ float crs[2][RPB];
    __shared__ float sred[4], sred2[4];

    if constexpr (FIRST) {
        // xT prep (first 288 flat blocks of 640)
        __shared__ __align__(16) ushort T[32][264];
        const int bid = blockIdx.x + 16 * blockIdx.y + 80 * blockIdx.z;
        if (bid < K1 / 32) {
            const int k0 = bid * 32;
            #pragma unroll
            for (int j = 0; j < 8; ++j) {
                int f  = j * 256 + tid;
                int b  = f >> 3;
                int i4 = f & 7;
                float4 v = *reinterpret_cast<const float4*>(
                    x + (size_t)b * K1 + k0 + i4 * 4);
                T[i4 * 4 + 0][b] = f2bf(v.x);
                T[i4 * 4 + 1][b] = f2bf(v.y);
                T[i4 * 4 + 2][b] = f2bf(v.z);
                T[i4 * 4 + 3][b] = f2bf(v.w);
            }
            __syncthreads();
            #pragma unroll
            for (int j = 0; j < 4; ++j) {
                int g   = j * 256 + tid;
                int row = g >> 5;
                int q8  = g & 31;
                *reinterpret_cast<uint4*>(xTbf + (size_t)(k0 + row) * NB + q8 * 8) =
                    *reinterpret_cast<const uint4*>(&T[row][q8 * 8]);
            }
        }
        const int nblk = 16 * 5 * KS;   // 640
        const size_t gs = (size_t)(blockIdx.x + 16 * blockIdx.y + 80 * blockIdx.z) * 256 + tid;
        // Wb = bf16(W), natural layout, coalesced
        for (size_t e = gs; e < (size_t)NR * NC * NO; e += (size_t)nblk * 256) {
            float4 v0 = *reinterpret_cast<const float4*>(W + e * 8);
            float4 v1 = *reinterpret_cast<const float4*>(W + e * 8 + 4);
            s16x8 p = pack8(v0, v1);
            *reinterpret_cast<uint4*>(Wb + e * 8) = *reinterpret_cast<uint4*>(&p);
        }
        // xbf = bf16(x), coalesced
        for (size_t e = gs; e < (size_t)NB * (K1 / 8); e += (size_t)nblk * 256) {
            float4 v0 = *reinterpret_cast<const float4*>(x + e * 8);
            float4 v1 = *reinterpret_cast<const float4*>(x + e * 8 + 4);
            s16x8 p = pack8(v0, v1);
            *reinterpret_cast<uint4*>(xbf + e * 8) = *reinterpret_cast<uint4*>(&p);
        }
    } else {
        // softmax stats per column (bbufT contiguous reads) -> crs[2][RPB]
        #pragma unroll
        for (int cc = 0; cc < 2; ++cc) {
            const float* bc = bbufT + (size_t)(c0 + cc) * NR;
            float m = -1e30f;
            for (int r = tid; r < NR; r += 256) m = fmaxf(m, bc[r]);
            #pragma unroll
            for (int off = 1; off < 64; off <<= 1) m = fmaxf(m, __shfl_xor(m, off));
            if (l == 0) sred[w] = m;
            __syncthreads();
            m = fmaxf(fmaxf(sred[0], sred[1]), fmaxf(sred[2], sred[3]));
            float s = 0.0f;
            for (int r = tid; r < NR; r += 256) s += expf(bc[r] - m);
            #pragma unroll
            for (int off = 1; off < 64; off <<= 1) s += __shfl_xor(s, off);
            if (l == 0) sred2[w] = s;
            __syncthreads();
            s = sred2[0] + sred2[1] + sred2[2] + sred2[3];
            const float inv = 1.0f / s;
            for (int i = tid; i < RPB; i += 256)
                crs[cc][i] = expf(bc[ks * RPB + i] - m) * inv;
            __syncthreads();
        }
    }

    const int kb = ks * KC + w * (KC / 4);   // wave K base (288)
    const int lg = l >> 4;

    f32x4 acc0 = {0.f, 0.f, 0.f, 0.f};
    f32x4 acc1 = {0.f, 0.f, 0.f, 0.f};
    if constexpr (FIRST) {
        const float* ap = x + (size_t)(m0 + (l & 15)) * K1 + kb + 8 * lg;
        #pragma unroll
        for (int kk = 0; kk < KC / 4 / 32; ++kk) {   // 9
            const int r = (kb + kk * 32 + 8 * lg) >> 3;
            float4 a0 = *reinterpret_cast<const float4*>(ap + kk * 32);
            float4 a1 = *reinterpret_cast<const float4*>(ap + kk * 32 + 4);
            s16x8 a = pack8s(a0, a1, 1.0f / NR);
            const float* wp = W + ((size_t)r * NC + c0) * 128 + (l & 15) * 8;
            s16x8 b0 = pack8(*reinterpret_cast<const float4*>(wp),
                             *reinterpret_cast<const float4*>(wp + 4));
            s16x8 b1 = pack8(*reinterpret_cast<const float4*>(wp + 128),
                             *reinterpret_cast<const float4*>(wp + 132));
            acc0 = __builtin_amdgcn_mfma_f32_16x16x32_bf16(a, b0, acc0, 0, 0, 0);
            acc1 = __builtin_amdgcn_mfma_f32_16x16x32_bf16(a, b1, acc1, 0, 0, 0);
        }
    } else {
        const ushort* ap = xbf + (size_t)(m0 + (l & 15)) * K1 + kb + 8 * lg;
        #pragma unroll
        for (int kk = 0; kk < KC / 4 / 32; ++kk) {   // 9
            const int r  = (kb + kk * 32 + 8 * lg) >> 3;
            const int ri = r - ks * RPB;
            uint4 ar = *reinterpret_cast<const uint4*>(ap + kk * 32);
            s16x8 a0 = scale8(ar, crs[0][ri]);
            s16x8 a1 = scale8(ar, crs[1][ri]);
            const ushort* wp = Wb + ((size_t)r * NC + c0) * 128 + (l & 15) * 8;
            s16x8 b0 = *reinterpret_cast<const s16x8*>(wp);
            s16x8 b1 = *reinterpret_cast<const s16x8*>(wp + 128);
            acc0 = __builtin_amdgcn_mfma_f32_16x16x32_bf16(a0, b0, acc0, 0, 0, 0);
            acc1 = __builtin_amdgcn_mfma_f32_16x16x32_bf16(a1, b1, acc1, 0, 0, 0);
        }
    }

    __syncthreads();
    #pragma unroll
    for (int q = 0; q < 4; ++q) {
        red[0][w][4 * lg + q][l & 15] = acc0[q];
        red[1][w][4 * lg + q][l & 15] = acc1[q];
    }
    __syncthreads();
    const int row = tid >> 4, col = tid & 15;
    #pragma unroll
    for (int cc = 0; cc < 2; ++cc) {
        float s2 = red[cc][0][row][col] + red[cc][1][row][col]
                 + red[cc][2][row][col] + red[cc][3][row][col];
        spart[(size_t)ks * (NB * NN) + (size_t)(m0 + row) * NN + (c0 + cc) * NO + col] = s2;
    }
}

// K_b: [sum spart -> squash -> VT in LDS] + GEMM2-from-LDS + W-contract ->
// exclusive bbufT update (transposed: [c][r], coalesced for k_a preamble).
__global__ __launch_bounds__(256) void k_b(const ushort* __restrict__ xTbf,
                                           const float* __restrict__ spart,
                                           const float* __restrict__ W,
                                           float* __restrict__ bbufT,
                                           int it) {
    const int c = blockIdx.y;
    const int tid = threadIdx.x;
    const int w = tid >> 6, l = tid & 63;

    __shared__ __align__(16) ushort VT[16][264];

    for (int f = tid; f < NB * NO; f += 256) {   // 4096 (b,oo)
        int b  = f >> 4;
        int oo = f & 15;
        size_t idx = (size_t)b * NN + c * NO + oo;
        float s = 0.0f;
        #pragma unroll
        for (int ks = 0; ks < KS; ++ks) s += spart[(size_t)ks * NB * NN + idx];
        float v = s * fabsf(s) / (1.0f + s * s);
        VT[oo][b] = f2bf(v);
    }
    __syncthreads();

    #pragma unroll
    for (int t = 0; t < 4; ++t) {
        const int mt = blockIdx.x * 16 + w * 4 + t;   // 0..575
        const int m0 = mt * 16;
        const ushort* ap = xTbf + (size_t)(m0 + (l & 15)) * NB + 8 * (l >> 4);
        f32x4 acc = {0.f, 0.f, 0.f, 0.f};
        #pragma unroll
        for (int kk = 0; kk < NB / 32; ++kk) {
            s16x8 a = *reinterpret_cast<const s16x8*>(ap + kk * 32);
            s16x8 b = *reinterpret_cast<const s16x8*>(&VT[l & 15][32 * kk + 8 * (l >> 4)]);
            acc = __builtin_amdgcn_mfma_f32_16x16x32_bf16(a, b, acc, 0, 0, 0);
        }
        const int h  = l >> 4, o = l & 15;
        const int r  = (m0 >> 3) + (h >> 1);
        const int i0 = (4 * h) & 7;
        const float4 w4 = *reinterpret_cast<const float4*>(
            W + (((size_t)r * NC + c) * NO + o) * NI + i0);
        float s = acc[0] * w4.x + acc[1] * w4.y + acc[2] * w4.z + acc[3] * w4.w;
        s += __shfl_xor(s, 1);
        s += __shfl_xor(s, 2);
        s += __shfl_xor(s, 4);
        s += __shfl_xor(s, 8);
        s += __shfl_xor(s, 16);
        if (l == 0 || l == 32) {
            int rr = (m0 >> 3) + (l >> 5);
            float val = s * (1.0f / NB);
            if (it > 0) bbufT[(size_t)c * NR + rr] += val;
            else        bbufT[(size_t)c * NR + rr] = val;
        }
    }
}

// final: sum spart slices + squash -> out[b][c][o]. Grid (16,10).
__global__ __launch_bounds__(256) void k_bf(const float* __restrict__ spart,
                                            float* __restrict__ out) {
    const int m0 = blockIdx.x * 16;
    const int c  = blockIdx.y;
    const int row = threadIdx.x >> 4, col = threadIdx.x & 15;
    size_t idx = (size_t)(m0 + row) * NN + c * NO + col;
    float s = 0.0f;
    #pragma unroll
    for (int ks = 0; ks < KS; ++ks) s += spart[(size_t)ks * NB * NN + idx];
    out[idx] = s * fabsf(s) / (1.0f + s * s);
}

extern "C" void kernel_launch(void* const* d_in, const int* in_sizes, int n_in,
                              void* d_out, int out_size, void* d_ws, size_t ws_size,
                              hipStream_t stream) {
    const float* x = (const float*)d_in[0];   // [256][9216]
    const float* W = (const float*)d_in[1];   // [1152,10,16,8]
    float* out = (float*)d_out;               // [256][160]

    // ws: spart | bbufT | xTbf | Wb | xbf  (~13.8 MB)
    float*  spart = (float*)d_ws;                          // 8*40960 f = 1.31 MB
    float*  bbufT = spart + (size_t)KS * NB * NN;          // 11520 f ([c][r])
    ushort* xTbf  = (ushort*)(bbufT + (size_t)NR * NC);    // 4.72 MB
    ushort* Wb    = xTbf + (size_t)K1 * NB;                // 2.95 MB
    ushort* xbf   = Wb + (size_t)NR * NC * NO * NI;        // 4.72 MB

    dim3 ga(NB / 16, NC / 2, KS);   // (16,5,8) = 640 blocks, N=32 per block
    dim3 gb(36, NC);                // 360 blocks
    dim3 gf(NB / 16, NC);           // 160 blocks

    k_a<true><<<ga, 256, 0, stream>>>(x, W, Wb, xbf, nullptr, spart, xTbf);
    k_b<<<gb, 256, 0, stream>>>(xTbf, spart, W, bbufT, 0);
    k_a<false><<<ga, 256, 0, stream>>>(x, W, Wb, xbf, bbufT, spart, nullptr);
    k_b<<<gb, 256, 0, stream>>>(xTbf, spart, W, bbufT, 1);
    k_a<false><<<ga, 256, 0, stream>>>(x, W, Wb, xbf, bbufT, spart, nullptr);
    k_bf<<<gf, 256, 0, stream>>>(spart, out);
}